// Round 1
// baseline (1466.641 us; speedup 1.0000x reference)
//
#include <hip/hip_runtime.h>

// N=8, CIN=256, CINT=192, COUT=128, K=3, L=512, H=W=128, OH=OW=256, IMG=3
// R3: pure-copy 16B staging for both MFMA GEMMs.
//  - xs[n][y][x][ci] bf16 pre-styled (lives in d_out, overwritten by conv later)
//  - h stored [n][oy][ox][192] bf16 with s_conv folded at upconv epilogue
//  - all LDS staging is dwordx4 -> ds_write_b128 (no float math in stage loops)
//  - conv epilogue float4 stores

using bfrag = __attribute__((ext_vector_type(8))) short;   // 8 bf16 (A/B frag)
using ffrag = __attribute__((ext_vector_type(4))) float;   // 4 f32 (C/D frag)

// ws float-index offsets (styles / inv-sigmas)
#define WS_S_UP      0        // 8*256
#define WS_ISIG_UP   2048     // 8*192
#define WS_S_CONV    3584     // 8*192
#define WS_ISIG_CONV 5120     // 8*128
#define WS_S_RGB     6144     // 8*128
// ws byte offsets (bf16 tensors)
#define WS_H_OFF     32768ull                       // ushort h[8][256][256][192]  (y,x,ci!)
#define H_ELEMS      (8ull*192*256*256)             // 100,663,296
#define WS_WUP_OFF   (WS_H_OFF + 2ull*H_ELEMS)      // wt_up_t[ky][kx][192 o][256 ci] bf16
#define WUP_ELEMS    (9*192*256)
#define WS_WCONV_OFF (WS_WUP_OFF + 2ull*WUP_ELEMS)  // wt_conv_t[tap][128 o][192 ci] bf16
#define WCONV_ELEMS  (9*128*192)

__device__ __forceinline__ unsigned short f2bf(float f) {
    unsigned u = __float_as_uint(f);
    return (unsigned short)((u + 0x7fffu + ((u >> 16) & 1u)) >> 16);
}

// ---------------------------------------------------------------------------
// Kernel 1: styles + inverse demod sigmas (fp32, unchanged)
// ---------------------------------------------------------------------------
__global__ __launch_bounds__(256) void style_kernel(
    const float* __restrict__ v,
    const float* __restrict__ sw_up, const float* __restrict__ sb_up,
    const float* __restrict__ w_up,
    const float* __restrict__ sw_conv, const float* __restrict__ sb_conv,
    const float* __restrict__ w_conv,
    const float* __restrict__ sw_rgb, const float* __restrict__ sb_rgb,
    float* __restrict__ ws)
{
    const int n = blockIdx.x;
    const int t = threadIdx.x;
    __shared__ float sup[256];
    __shared__ float sconv[192];
    const float* vp = v + n * 512;
    {
        float a = 0.f;
        const float* r = sw_up + (size_t)t * 512;
        for (int l = 0; l < 512; ++l) a = fmaf(vp[l], r[l], a);
        float s = a + sb_up[t] + 1.0f;
        sup[t] = s;
        ws[WS_S_UP + n * 256 + t] = s;
    }
    if (t < 192) {
        float a = 0.f;
        const float* r = sw_conv + (size_t)t * 512;
        for (int l = 0; l < 512; ++l) a = fmaf(vp[l], r[l], a);
        float s = a + sb_conv[t] + 1.0f;
        sconv[t] = s;
        ws[WS_S_CONV + n * 192 + t] = s;
    }
    if (t < 128) {
        float a = 0.f;
        const float* r = sw_rgb + (size_t)t * 512;
        for (int l = 0; l < 512; ++l) a = fmaf(vp[l], r[l], a);
        ws[WS_S_RGB + n * 128 + t] = a + sb_rgb[t] + 1.0f;
    }
    __syncthreads();
    if (t < 192) {
        float sum = 0.f;
        for (int i = 0; i < 256; ++i) {
            const float* w = w_up + ((size_t)i * 192 + t) * 9;
            float wsq = 0.f;
            #pragma unroll
            for (int k = 0; k < 9; ++k) wsq = fmaf(w[k], w[k], wsq);
            sum = fmaf(sup[i] * sup[i], wsq, sum);
        }
        ws[WS_ISIG_UP + n * 192 + t] = 1.0f / sqrtf(sum + 1e-8f);
    }
    if (t < 128) {
        float sum = 0.f;
        for (int i = 0; i < 192; ++i) {
            const float* w = w_conv + ((size_t)t * 192 + i) * 9;
            float wsq = 0.f;
            #pragma unroll
            for (int k = 0; k < 9; ++k) wsq = fmaf(w[k], w[k], wsq);
            sum = fmaf(sconv[i] * sconv[i], wsq, sum);
        }
        ws[WS_ISIG_CONV + n * 128 + t] = 1.0f / sqrtf(sum + 1e-8f);
    }
}

// ---------------------------------------------------------------------------
// Weight prepack (unchanged): [tap][o][ci] bf16, ci contiguous
// ---------------------------------------------------------------------------
__global__ __launch_bounds__(256) void prepack_up(
    const float* __restrict__ w_up, unsigned short* __restrict__ out)
{
    int idx = blockIdx.x * 256 + threadIdx.x;
    if (idx >= WUP_ELEMS) return;
    int ci = idx & 255;
    int rest = idx >> 8;          // t*192 + o
    int o = rest % 192;
    int t = rest / 192;
    out[idx] = f2bf(w_up[((size_t)(ci * 192 + o)) * 9 + t]);
}

__global__ __launch_bounds__(256) void prepack_conv(
    const float* __restrict__ w_conv, unsigned short* __restrict__ out)
{
    int idx = blockIdx.x * 256 + threadIdx.x;
    if (idx >= WCONV_ELEMS) return;
    int ci = idx % 192;
    int rest = idx / 192;         // t*128 + o
    int o = rest & 127;
    int t = rest >> 7;
    out[idx] = f2bf(w_conv[((size_t)(o * 192 + ci)) * 9 + t]);
}

// ---------------------------------------------------------------------------
// Kernel 1b: pre-style + transpose x -> xs[n][y][x][256 ci] bf16.
// LDS-transposed so both global read (along x) and write (along ci) coalesce.
// ---------------------------------------------------------------------------
__global__ __launch_bounds__(256) void prestyle_x(
    const float* __restrict__ x, const float* __restrict__ ws,
    unsigned short* __restrict__ xs)
{
    const int n = blockIdx.x >> 7;
    const int y = blockIdx.x & 127;
    const int tid = threadIdx.x;
    __shared__ unsigned short st[128 * 72];   // [x][64 ci + pad], 16B-aligned rows

    for (int cc0 = 0; cc0 < 256; cc0 += 64) {
        if (cc0) __syncthreads();
        for (int idx = tid; idx < 64 * 128; idx += 256) {
            int c = idx >> 7;
            int xx = idx & 127;
            float s = ws[WS_S_UP + n * 256 + cc0 + c];
            float val = x[(((size_t)n * 256 + cc0 + c) * 128 + y) * 128 + xx] * s;
            st[xx * 72 + c] = f2bf(val);
        }
        __syncthreads();
        for (int idx = tid; idx < 128 * 8; idx += 256) {
            int xp = idx >> 3;
            int part = idx & 7;
            int4 v = *(const int4*)&st[xp * 72 + part * 8];
            *(int4*)&xs[(((size_t)n * 128 + y) * 128 + xp) * 256 + cc0 + part * 8] = v;
        }
    }
}

// ---------------------------------------------------------------------------
// Kernel 2: upconv as MFMA GEMM.  Block = (n, oy, x-parity, o-half 96).
// A-stage is now a pure 16B copy from pre-styled xs.
// ---------------------------------------------------------------------------
__global__ __launch_bounds__(256, 2) void upconv_mfma(
    const unsigned short* __restrict__ xs, const unsigned short* __restrict__ wt,
    const float* __restrict__ b_up, const float* __restrict__ noise1,
    const float* __restrict__ ns1p, const float* __restrict__ ws,
    unsigned short* __restrict__ h)
{
    const int oy  = blockIdx.y;
    const int n   = blockIdx.z;
    const int px  = blockIdx.x & 1;
    const int O0  = (blockIdx.x >> 1) * 96;
    const int py  = oy & 1;
    const int iy0 = oy >> 1;
    const int rows = 1 + py;
    const int ntx  = 1 + px;
    const int ntaps = rows * ntx;

    const int tid  = threadIdx.x;
    const int wave = __builtin_amdgcn_readfirstlane(tid >> 6);
    const int lane = tid & 63;
    const int lm = lane & 15, quad = lane >> 4, k0 = quad * 8;
    const int wy = wave >> 1;   // m-half (64 px)
    const int wx = wave & 1;    // n-half (48 ch)

    __shared__ __align__(16) unsigned short As[2 * 132 * 40];  // [row][xx 0..128][ci pad40]
    __shared__ __align__(16) unsigned short Bs[4 * 96 * 40];   // [tap][o][ci pad40]

    ffrag acc[4][3] = {};

    for (int c0 = 0; c0 < 256; c0 += 32) {
        __syncthreads();
        // stage A: rows*129*4 16B units, pure copy from xs
        {
            const int tot = rows * 516;          // 129*4
            for (int idx = tid; idx < tot; idx += 256) {
                int r = idx / 516;
                int rem = idx - r * 516;
                int xx = rem >> 2, u = rem & 3;
                int iy = iy0 + r;
                int4 v = {0, 0, 0, 0};
                if (iy < 128 && xx < 128)
                    v = *(const int4*)&xs[(((size_t)n * 128 + iy) * 128 + xx) * 256 + c0 + u * 8];
                *(int4*)&As[(r * 132 + xx) * 40 + u * 8] = v;
            }
        }
        // stage B: ntaps*96*4 16B units
        {
            const int tot = ntaps * 384;
            for (int idx = tid; idx < tot; idx += 256) {
                int t = idx / 384;
                int rem = idx - t * 384;
                int o = rem >> 2, u = rem & 3;
                int rs = (ntx == 2) ? (t >> 1) : t;
                int cs = (ntx == 2) ? (t & 1) : 0;
                int ky = py ? (rs ? 0 : 2) : 1;
                int kx = px ? (cs ? 0 : 2) : 1;
                int4 v = *(const int4*)&wt[
                    (((size_t)(ky * 3 + kx) * 192 + O0 + o) * 256) + c0 + u * 8];
                *(int4*)&Bs[(t * 96 + o) * 40 + u * 8] = v;
            }
        }
        __syncthreads();
        for (int t = 0; t < ntaps; ++t) {
            int rs = (ntx == 2) ? (t >> 1) : t;
            int cs = (ntx == 2) ? (t & 1) : 0;
            bfrag b[3];
            #pragma unroll
            for (int tn = 0; tn < 3; ++tn)
                b[tn] = *(const bfrag*)&Bs[(t * 96 + wx * 48 + tn * 16 + lm) * 40 + k0];
            #pragma unroll
            for (int tm = 0; tm < 4; ++tm) {
                bfrag a = *(const bfrag*)&As[(rs * 132 + wy * 64 + tm * 16 + lm + cs) * 40 + k0];
                #pragma unroll
                for (int tn = 0; tn < 3; ++tn)
                    acc[tm][tn] = __builtin_amdgcn_mfma_f32_16x16x32_bf16(a, b[tn], acc[tm][tn], 0, 0, 0);
            }
        }
    }

    // epilogue: demod + bias + noise + leaky, then fold s_conv, write [oy][ox][ci]
    const float ns1 = ns1p[0];
    const float* isig  = ws + WS_ISIG_UP + n * 192;
    const float* sconv = ws + WS_S_CONV + n * 192;
    #pragma unroll
    for (int tn = 0; tn < 3; ++tn) {
        const int o = O0 + wx * 48 + tn * 16 + lm;
        const float sg = isig[o];
        const float bb = b_up[o];
        const float sc = sconv[o];
        #pragma unroll
        for (int tm = 0; tm < 4; ++tm) {
            #pragma unroll
            for (int r = 0; r < 4; ++r) {
                int m = wy * 64 + tm * 16 + quad * 4 + r;   // C/D: row=quad*4+reg, col=lane&15
                int ox = 2 * m + px;
                float val = acc[tm][tn][r] * sg + bb
                          + ns1 * noise1[((size_t)n * 256 + oy) * 256 + ox];
                val = val > 0.f ? val : 0.2f * val;
                h[(((size_t)n * 256 + oy) * 256 + ox) * 192 + o] = f2bf(val * sc);
            }
        }
    }
}

// ---------------------------------------------------------------------------
// Kernel 3: 3x3 conv as MFMA GEMM. h is [n][y][x][192] bf16, style pre-folded,
// so A-stage is a pure aligned 16B copy. Block = (n, oy, x-half).
// ---------------------------------------------------------------------------
__global__ __launch_bounds__(256, 2) void conv_mfma(
    const unsigned short* __restrict__ h, const unsigned short* __restrict__ wt,
    const float* __restrict__ b_conv, const float* __restrict__ noise2,
    const float* __restrict__ ns2p, const float* __restrict__ ws,
    float* __restrict__ h2)
{
    const int oy = blockIdx.y;
    const int n  = blockIdx.z;
    const int X0 = (blockIdx.x & 1) * 128;
    const int tid  = threadIdx.x;
    const int wave = __builtin_amdgcn_readfirstlane(tid >> 6);
    const int lane = tid & 63;
    const int lm = lane & 15, quad = lane >> 4, k0 = quad * 8;
    const int wy = wave >> 1, wx = wave & 1;

    __shared__ __align__(16) unsigned short As[3 * 132 * 40];  // [dy][xx 0..129][ci pad40]
    __shared__ __align__(16) unsigned short Bs[3 * 128 * 40];  // [dx][o][ci pad40]

    ffrag acc[4][4] = {};

    for (int c0 = 0; c0 < 192; c0 += 32) {
        __syncthreads();
        // stage A: 3*130*4 16B units, pure copy with edge zeroing
        for (int idx = tid; idx < 1560; idx += 256) {
            int r = idx / 520;
            int rem = idx - r * 520;
            int xx = rem >> 2, u = rem & 3;
            int iy = oy - 1 + r;
            int ix = X0 - 1 + xx;
            int4 v = {0, 0, 0, 0};
            if (iy >= 0 && iy < 256 && ix >= 0 && ix < 256)
                v = *(const int4*)&h[(((size_t)n * 256 + iy) * 256 + ix) * 192 + c0 + u * 8];
            *(int4*)&As[(r * 132 + xx) * 40 + u * 8] = v;
        }
        for (int dy = 0; dy < 3; ++dy) {
            if (dy) __syncthreads();
            // stage B: 3 dx taps, 3*128*4 16B units
            for (int idx = tid; idx < 1536; idx += 256) {
                int dx = idx >> 9;
                int rem = idx & 511;
                int o = rem >> 2, u = rem & 3;
                int4 v = *(const int4*)&wt[
                    (((size_t)(dy * 3 + dx) * 128 + o) * 192) + c0 + u * 8];
                *(int4*)&Bs[(dx * 128 + o) * 40 + u * 8] = v;
            }
            __syncthreads();
            #pragma unroll
            for (int dx = 0; dx < 3; ++dx) {
                bfrag b[4];
                #pragma unroll
                for (int tn = 0; tn < 4; ++tn)
                    b[tn] = *(const bfrag*)&Bs[(dx * 128 + wx * 64 + tn * 16 + lm) * 40 + k0];
                #pragma unroll
                for (int tm = 0; tm < 4; ++tm) {
                    bfrag a = *(const bfrag*)&As[(dy * 132 + wy * 64 + tm * 16 + lm + dx) * 40 + k0];
                    #pragma unroll
                    for (int tn = 0; tn < 4; ++tn)
                        acc[tm][tn] = __builtin_amdgcn_mfma_f32_16x16x32_bf16(a, b[tn], acc[tm][tn], 0, 0, 0);
                }
            }
        }
    }

    const float ns2 = ns2p[0];
    const float* isig = ws + WS_ISIG_CONV + n * 128;
    #pragma unroll
    for (int tn = 0; tn < 4; ++tn) {
        const int o = wx * 64 + tn * 16 + lm;
        const float sg = isig[o];
        const float bb = b_conv[o];
        #pragma unroll
        for (int tm = 0; tm < 4; ++tm) {
            const int ox0 = X0 + wy * 64 + tm * 16 + quad * 4;
            float4 nz = *(const float4*)&noise2[((size_t)n * 256 + oy) * 256 + ox0];
            float4 outv;
            float val;
            val = acc[tm][tn][0] * sg + bb + ns2 * nz.x; outv.x = val > 0.f ? val : 0.2f * val;
            val = acc[tm][tn][1] * sg + bb + ns2 * nz.y; outv.y = val > 0.f ? val : 0.2f * val;
            val = acc[tm][tn][2] * sg + bb + ns2 * nz.z; outv.z = val > 0.f ? val : 0.2f * val;
            val = acc[tm][tn][3] * sg + bb + ns2 * nz.w; outv.w = val > 0.f ? val : 0.2f * val;
            *(float4*)&h2[(((size_t)n * 128 + o) * 256 + oy) * 256 + ox0] = outv;
        }
    }
}

// ---------------------------------------------------------------------------
// Kernel 4: to_rgb (1x1 modulated, no demod) + act + bilinear skip (unchanged)
// ---------------------------------------------------------------------------
__global__ __launch_bounds__(256) void rgb_kernel(
    const float* __restrict__ h2, const float* __restrict__ w_rgb,
    const float* __restrict__ b_rgb, const float* __restrict__ y,
    const float* __restrict__ ws, float* __restrict__ yout)
{
    const int bid = blockIdx.x;
    const int n   = bid >> 8;
    const int pix = ((bid & 255) << 8) + threadIdx.x;
    const int oy  = pix >> 8, ox = pix & 255;

    __shared__ float cw0[128], cw1[128], cw2[128];
    if (threadIdx.x < 128) {
        float s = ws[WS_S_RGB + n * 128 + threadIdx.x];
        cw0[threadIdx.x] = w_rgb[0 * 128 + threadIdx.x] * s;
        cw1[threadIdx.x] = w_rgb[1 * 128 + threadIdx.x] * s;
        cw2[threadIdx.x] = w_rgb[2 * 128 + threadIdx.x] * s;
    }
    __syncthreads();

    const float* hp = h2 + (size_t)n * 128 * 65536 + oy * 256 + ox;
    float a0 = 0.f, a1 = 0.f, a2 = 0.f;
    for (int i = 0; i < 128; ++i) {
        float hv = hp[(size_t)i * 65536];
        a0 = fmaf(hv, cw0[i], a0);
        a1 = fmaf(hv, cw1[i], a1);
        a2 = fmaf(hv, cw2[i], a2);
    }

    const int m = oy >> 1;
    int iy0, iy1; float wy0, wy1;
    if ((oy & 1) == 0) { iy0 = m > 0 ? m - 1 : 0; iy1 = m; wy0 = 0.25f; wy1 = 0.75f; }
    else               { iy0 = m; iy1 = m < 127 ? m + 1 : 127; wy0 = 0.75f; wy1 = 0.25f; }
    const int mm = ox >> 1;
    int ix0, ix1; float wx0, wx1;
    if ((ox & 1) == 0) { ix0 = mm > 0 ? mm - 1 : 0; ix1 = mm; wx0 = 0.25f; wx1 = 0.75f; }
    else               { ix0 = mm; ix1 = mm < 127 ? mm + 1 : 127; wx0 = 0.75f; wx1 = 0.25f; }

    float r[3] = { a0 + b_rgb[0], a1 + b_rgb[1], a2 + b_rgb[2] };
    #pragma unroll
    for (int c = 0; c < 3; ++c) {
        float t = r[c];
        t = t > 0.f ? t : 0.2f * t;
        const float* yp = y + ((size_t)n * 3 + c) * 128 * 128;
        float yu = wy0 * (wx0 * yp[iy0 * 128 + ix0] + wx1 * yp[iy0 * 128 + ix1])
                 + wy1 * (wx0 * yp[iy1 * 128 + ix0] + wx1 * yp[iy1 * 128 + ix1]);
        yout[(((size_t)n * 3 + c) * 256 + oy) * 256 + ox] = yu + t;
    }
}

// ---------------------------------------------------------------------------
extern "C" void kernel_launch(void* const* d_in, const int* in_sizes, int n_in,
                              void* d_out, int out_size, void* d_ws, size_t ws_size,
                              hipStream_t stream)
{
    const float* x       = (const float*)d_in[0];
    const float* v       = (const float*)d_in[1];
    const float* y       = (const float*)d_in[2];
    const float* noise1  = (const float*)d_in[3];
    const float* noise2  = (const float*)d_in[4];
    const float* w_up    = (const float*)d_in[5];
    const float* b_up    = (const float*)d_in[6];
    const float* sw_up   = (const float*)d_in[7];
    const float* sb_up   = (const float*)d_in[8];
    const float* w_conv  = (const float*)d_in[9];
    const float* b_conv  = (const float*)d_in[10];
    const float* sw_conv = (const float*)d_in[11];
    const float* sb_conv = (const float*)d_in[12];
    const float* w_rgb   = (const float*)d_in[13];
    const float* b_rgb   = (const float*)d_in[14];
    const float* sw_rgb  = (const float*)d_in[15];
    const float* sb_rgb  = (const float*)d_in[16];
    const float* ns1     = (const float*)d_in[17];
    const float* ns2     = (const float*)d_in[18];

    float* ws = (float*)d_ws;
    unsigned short* h       = (unsigned short*)((char*)d_ws + WS_H_OFF);
    unsigned short* wt_up   = (unsigned short*)((char*)d_ws + WS_WUP_OFF);
    unsigned short* wt_conv = (unsigned short*)((char*)d_ws + WS_WCONV_OFF);
    float* h2   = (float*)d_out;                 // [8,128,256,256]
    float* yout = h2 + (size_t)67108864;         // [8,3,256,256]
    // xs[8][128][128][256] bf16 = 67.1 MB, parked in the h2 region of d_out.
    // Consumed by upconv_mfma before conv_mfma overwrites the region with h2.
    unsigned short* xs = (unsigned short*)d_out;

    style_kernel<<<8, 256, 0, stream>>>(v, sw_up, sb_up, w_up, sw_conv, sb_conv,
                                        w_conv, sw_rgb, sb_rgb, ws);
    prepack_up<<<(WUP_ELEMS + 255) / 256, 256, 0, stream>>>(w_up, wt_up);
    prepack_conv<<<(WCONV_ELEMS + 255) / 256, 256, 0, stream>>>(w_conv, wt_conv);
    prestyle_x<<<1024, 256, 0, stream>>>(x, ws, xs);
    upconv_mfma<<<dim3(4, 256, 8), 256, 0, stream>>>(xs, wt_up, b_up, noise1, ns1, ws, h);
    conv_mfma<<<dim3(2, 256, 8), 256, 0, stream>>>(h, wt_conv, b_conv, noise2, ns2, ws, h2);
    rgb_kernel<<<2048, 256, 0, stream>>>(h2, w_rgb, b_rgb, y, ws, yout);
}

// Round 2
// 1158.640 us; speedup vs baseline: 1.2658x; 1.2658x over previous
//
#include <hip/hip_runtime.h>

// N=8, CIN=256, CINT=192, COUT=128, K=3, L=512, H=W=128, OH=OW=256, IMG=3
// R4: B-operands moved from LDS to registers via fragment-major weight prepack.
//  - wt_* prepacked as [tap][kc][ob][lane][8] bf16 so a B-frag is ONE coalesced
//    global_load_dwordx4 per wave (L2-resident, 442/884 KB).
//  - LDS now holds only As: conv 31.7KB (5 blk/CU), upconv 21.1KB.
//  - barriers per block: conv 42 -> 12, upconv 16.

using bfrag = __attribute__((ext_vector_type(8))) short;   // 8 bf16 (A/B frag)
using ffrag = __attribute__((ext_vector_type(4))) float;   // 4 f32 (C/D frag)

// ws float-index offsets (styles / inv-sigmas)
#define WS_S_UP      0        // 8*256
#define WS_ISIG_UP   2048     // 8*192
#define WS_S_CONV    3584     // 8*192
#define WS_ISIG_CONV 5120     // 8*128
#define WS_S_RGB     6144     // 8*128
// ws byte offsets (bf16 tensors)
#define WS_H_OFF     32768ull                       // ushort h[8][256][256][192]  (y,x,ci!)
#define H_ELEMS      (8ull*192*256*256)             // 100,663,296
#define WS_WUP_OFF   (WS_H_OFF + 2ull*H_ELEMS)      // frag-major up weights
#define WUP_ELEMS    (9*8*12*64*8)                  // 442368 (tap,kc,ob,lane,e)
#define WS_WCONV_OFF (WS_WUP_OFF + 2ull*WUP_ELEMS)  // frag-major conv weights
#define WCONV_ELEMS  (9*6*8*64*8)                   // 221184

__device__ __forceinline__ unsigned short f2bf(float f) {
    unsigned u = __float_as_uint(f);
    return (unsigned short)((u + 0x7fffu + ((u >> 16) & 1u)) >> 16);
}

// ---------------------------------------------------------------------------
// Kernel 1: styles + inverse demod sigmas (fp32, unchanged)
// ---------------------------------------------------------------------------
__global__ __launch_bounds__(256) void style_kernel(
    const float* __restrict__ v,
    const float* __restrict__ sw_up, const float* __restrict__ sb_up,
    const float* __restrict__ w_up,
    const float* __restrict__ sw_conv, const float* __restrict__ sb_conv,
    const float* __restrict__ w_conv,
    const float* __restrict__ sw_rgb, const float* __restrict__ sb_rgb,
    float* __restrict__ ws)
{
    const int n = blockIdx.x;
    const int t = threadIdx.x;
    __shared__ float sup[256];
    __shared__ float sconv[192];
    const float* vp = v + n * 512;
    {
        float a = 0.f;
        const float* r = sw_up + (size_t)t * 512;
        for (int l = 0; l < 512; ++l) a = fmaf(vp[l], r[l], a);
        float s = a + sb_up[t] + 1.0f;
        sup[t] = s;
        ws[WS_S_UP + n * 256 + t] = s;
    }
    if (t < 192) {
        float a = 0.f;
        const float* r = sw_conv + (size_t)t * 512;
        for (int l = 0; l < 512; ++l) a = fmaf(vp[l], r[l], a);
        float s = a + sb_conv[t] + 1.0f;
        sconv[t] = s;
        ws[WS_S_CONV + n * 192 + t] = s;
    }
    if (t < 128) {
        float a = 0.f;
        const float* r = sw_rgb + (size_t)t * 512;
        for (int l = 0; l < 512; ++l) a = fmaf(vp[l], r[l], a);
        ws[WS_S_RGB + n * 128 + t] = a + sb_rgb[t] + 1.0f;
    }
    __syncthreads();
    if (t < 192) {
        float sum = 0.f;
        for (int i = 0; i < 256; ++i) {
            const float* w = w_up + ((size_t)i * 192 + t) * 9;
            float wsq = 0.f;
            #pragma unroll
            for (int k = 0; k < 9; ++k) wsq = fmaf(w[k], w[k], wsq);
            sum = fmaf(sup[i] * sup[i], wsq, sum);
        }
        ws[WS_ISIG_UP + n * 192 + t] = 1.0f / sqrtf(sum + 1e-8f);
    }
    if (t < 128) {
        float sum = 0.f;
        for (int i = 0; i < 192; ++i) {
            const float* w = w_conv + ((size_t)t * 192 + i) * 9;
            float wsq = 0.f;
            #pragma unroll
            for (int k = 0; k < 9; ++k) wsq = fmaf(w[k], w[k], wsq);
            sum = fmaf(sconv[i] * sconv[i], wsq, sum);
        }
        ws[WS_ISIG_CONV + n * 128 + t] = 1.0f / sqrtf(sum + 1e-8f);
    }
}

// ---------------------------------------------------------------------------
// Weight prepack: fragment-major. frag = ((tap*KC + kc)*OB + ob); each frag is
// 64 lanes x 8 bf16: elem(lane,e) = W[o = ob*16 + (lane&15)][ci = kc*32 + (lane>>4)*8 + e]
// ---------------------------------------------------------------------------
__global__ __launch_bounds__(256) void prepack_up(
    const float* __restrict__ w_up, unsigned short* __restrict__ out)
{
    int t = blockIdx.x * 256 + threadIdx.x;   // frag*64 + lane
    if (t >= 9 * 8 * 12 * 64) return;
    int lane = t & 63;
    int f = t >> 6;                           // (tap*8 + kc)*12 + ob
    int ob = f % 12;
    int rest = f / 12;
    int kc = rest & 7;
    int tap = rest >> 3;
    int o = ob * 16 + (lane & 15);
    int ci0 = kc * 32 + (lane >> 4) * 8;
    unsigned short tmp[8];
    #pragma unroll
    for (int e = 0; e < 8; ++e)               // w_up layout [ci][o][tap]
        tmp[e] = f2bf(w_up[((size_t)((ci0 + e) * 192 + o)) * 9 + tap]);
    *(int4*)&out[(size_t)t * 8] = *(const int4*)tmp;
}

__global__ __launch_bounds__(256) void prepack_conv(
    const float* __restrict__ w_conv, unsigned short* __restrict__ out)
{
    int t = blockIdx.x * 256 + threadIdx.x;
    if (t >= 9 * 6 * 8 * 64) return;
    int lane = t & 63;
    int f = t >> 6;                           // (tap*6 + kc)*8 + ob
    int ob = f & 7;
    int rest = f >> 3;
    int kc = rest % 6;
    int tap = rest / 6;
    int o = ob * 16 + (lane & 15);
    int ci0 = kc * 32 + (lane >> 4) * 8;
    unsigned short tmp[8];
    #pragma unroll
    for (int e = 0; e < 8; ++e)               // w_conv layout [o][ci][tap]
        tmp[e] = f2bf(w_conv[((size_t)(o * 192 + ci0 + e)) * 9 + tap]);
    *(int4*)&out[(size_t)t * 8] = *(const int4*)tmp;
}

// ---------------------------------------------------------------------------
// Kernel 1b: pre-style + transpose x -> xs[n][y][x][256 ci] bf16 (unchanged)
// ---------------------------------------------------------------------------
__global__ __launch_bounds__(256) void prestyle_x(
    const float* __restrict__ x, const float* __restrict__ ws,
    unsigned short* __restrict__ xs)
{
    const int n = blockIdx.x >> 7;
    const int y = blockIdx.x & 127;
    const int tid = threadIdx.x;
    __shared__ unsigned short st[128 * 72];   // [x][64 ci + pad]

    for (int cc0 = 0; cc0 < 256; cc0 += 64) {
        if (cc0) __syncthreads();
        for (int idx = tid; idx < 64 * 128; idx += 256) {
            int c = idx >> 7;
            int xx = idx & 127;
            float s = ws[WS_S_UP + n * 256 + cc0 + c];
            float val = x[(((size_t)n * 256 + cc0 + c) * 128 + y) * 128 + xx] * s;
            st[xx * 72 + c] = f2bf(val);
        }
        __syncthreads();
        for (int idx = tid; idx < 128 * 8; idx += 256) {
            int xp = idx >> 3;
            int part = idx & 7;
            int4 v = *(const int4*)&st[xp * 72 + part * 8];
            *(int4*)&xs[(((size_t)n * 128 + y) * 128 + xp) * 256 + cc0 + part * 8] = v;
        }
    }
}

// ---------------------------------------------------------------------------
// Kernel 2: upconv MFMA GEMM. B-frags from registers (frag-major global).
// LDS = As only (21.1 KB).
// ---------------------------------------------------------------------------
__global__ __launch_bounds__(256, 4) void upconv_mfma(
    const unsigned short* __restrict__ xs, const unsigned short* __restrict__ wt,
    const float* __restrict__ b_up, const float* __restrict__ noise1,
    const float* __restrict__ ns1p, const float* __restrict__ ws,
    unsigned short* __restrict__ h)
{
    const int oy  = blockIdx.y;
    const int n   = blockIdx.z;
    const int px  = blockIdx.x & 1;
    const int O0  = (blockIdx.x >> 1) * 96;
    const int py  = oy & 1;
    const int iy0 = oy >> 1;
    const int rows = 1 + py;
    const int ntx  = 1 + px;
    const int ntaps = rows * ntx;

    const int tid  = threadIdx.x;
    const int wave = __builtin_amdgcn_readfirstlane(tid >> 6);
    const int lane = tid & 63;
    const int lm = lane & 15, quad = lane >> 4, k0 = quad * 8;
    const int wy = wave >> 1;   // m-half (64 px)
    const int wx = wave & 1;    // n-half (48 ch)

    __shared__ __align__(16) unsigned short As[2 * 132 * 40];  // [row][xx 0..128][ci pad40]

    const bfrag* Bf = (const bfrag*)wt;       // 16B frag units
    const int ob_base = (blockIdx.x >> 1) * 6 + wx * 3;   // o-block (of 16) for tn=0

    ffrag acc[4][3] = {};

    for (int kc = 0; kc < 8; ++kc) {
        const int c0 = kc * 32;
        __syncthreads();
        // stage A: rows*129*4 16B units, pure copy from xs
        {
            const int tot = rows * 516;          // 129*4
            for (int idx = tid; idx < tot; idx += 256) {
                int r = idx / 516;
                int rem = idx - r * 516;
                int xx = rem >> 2, u = rem & 3;
                int iy = iy0 + r;
                int4 v = {0, 0, 0, 0};
                if (iy < 128 && xx < 128)
                    v = *(const int4*)&xs[(((size_t)n * 128 + iy) * 128 + xx) * 256 + c0 + u * 8];
                *(int4*)&As[(r * 132 + xx) * 40 + u * 8] = v;
            }
        }
        __syncthreads();
        for (int t = 0; t < ntaps; ++t) {
            int rs = (ntx == 2) ? (t >> 1) : t;
            int cs = (ntx == 2) ? (t & 1) : 0;
            int ky = py ? (rs ? 0 : 2) : 1;
            int kx = px ? (cs ? 0 : 2) : 1;
            const bfrag* bp = Bf + ((size_t)(((ky * 3 + kx) * 8 + kc) * 12 + ob_base)) * 64 + lane;
            bfrag b[3];
            #pragma unroll
            for (int tn = 0; tn < 3; ++tn)
                b[tn] = bp[tn * 64];             // coalesced 1KB global load, L2-hit
            #pragma unroll
            for (int tm = 0; tm < 4; ++tm) {
                bfrag a = *(const bfrag*)&As[(rs * 132 + wy * 64 + tm * 16 + lm + cs) * 40 + k0];
                #pragma unroll
                for (int tn = 0; tn < 3; ++tn)
                    acc[tm][tn] = __builtin_amdgcn_mfma_f32_16x16x32_bf16(a, b[tn], acc[tm][tn], 0, 0, 0);
            }
        }
    }

    // epilogue: demod + bias + noise + leaky, fold s_conv, write [oy][ox][ci]
    const float ns1 = ns1p[0];
    const float* isig  = ws + WS_ISIG_UP + n * 192;
    const float* sconv = ws + WS_S_CONV + n * 192;
    #pragma unroll
    for (int tn = 0; tn < 3; ++tn) {
        const int o = O0 + wx * 48 + tn * 16 + lm;
        const float sg = isig[o];
        const float bb = b_up[o];
        const float sc = sconv[o];
        #pragma unroll
        for (int tm = 0; tm < 4; ++tm) {
            #pragma unroll
            for (int r = 0; r < 4; ++r) {
                int m = wy * 64 + tm * 16 + quad * 4 + r;   // C/D: row=quad*4+reg, col=lane&15
                int ox = 2 * m + px;
                float val = acc[tm][tn][r] * sg + bb
                          + ns1 * noise1[((size_t)n * 256 + oy) * 256 + ox];
                val = val > 0.f ? val : 0.2f * val;
                h[(((size_t)n * 256 + oy) * 256 + ox) * 192 + o] = f2bf(val * sc);
            }
        }
    }
}

// ---------------------------------------------------------------------------
// Kernel 3: 3x3 conv MFMA GEMM. B-frags from registers; LDS = As only (31.7 KB).
// ---------------------------------------------------------------------------
__global__ __launch_bounds__(256, 4) void conv_mfma(
    const unsigned short* __restrict__ h, const unsigned short* __restrict__ wt,
    const float* __restrict__ b_conv, const float* __restrict__ noise2,
    const float* __restrict__ ns2p, const float* __restrict__ ws,
    float* __restrict__ h2)
{
    const int oy = blockIdx.y;
    const int n  = blockIdx.z;
    const int X0 = (blockIdx.x & 1) * 128;
    const int tid  = threadIdx.x;
    const int wave = __builtin_amdgcn_readfirstlane(tid >> 6);
    const int lane = tid & 63;
    const int lm = lane & 15, quad = lane >> 4, k0 = quad * 8;
    const int wy = wave >> 1, wx = wave & 1;

    __shared__ __align__(16) unsigned short As[3 * 132 * 40];  // [dy][xx 0..129][ci pad40]

    const bfrag* Bf = (const bfrag*)wt;
    const int ob_base = wx * 4;

    ffrag acc[4][4] = {};

    for (int kc = 0; kc < 6; ++kc) {
        const int c0 = kc * 32;
        __syncthreads();
        // stage A: 3*130*4 16B units, pure copy with edge zeroing
        for (int idx = tid; idx < 1560; idx += 256) {
            int r = idx / 520;
            int rem = idx - r * 520;
            int xx = rem >> 2, u = rem & 3;
            int iy = oy - 1 + r;
            int ix = X0 - 1 + xx;
            int4 v = {0, 0, 0, 0};
            if (iy >= 0 && iy < 256 && ix >= 0 && ix < 256)
                v = *(const int4*)&h[(((size_t)n * 256 + iy) * 256 + ix) * 192 + c0 + u * 8];
            *(int4*)&As[(r * 132 + xx) * 40 + u * 8] = v;
        }
        __syncthreads();
        for (int dy = 0; dy < 3; ++dy) {
            for (int dx = 0; dx < 3; ++dx) {
                const bfrag* bp = Bf + ((size_t)(((dy * 3 + dx) * 6 + kc) * 8 + ob_base)) * 64 + lane;
                bfrag b[4];
                #pragma unroll
                for (int tn = 0; tn < 4; ++tn)
                    b[tn] = bp[tn * 64];         // coalesced 1KB global load, L2-hit
                #pragma unroll
                for (int tm = 0; tm < 4; ++tm) {
                    bfrag a = *(const bfrag*)&As[(dy * 132 + wy * 64 + tm * 16 + lm + dx) * 40 + k0];
                    #pragma unroll
                    for (int tn = 0; tn < 4; ++tn)
                        acc[tm][tn] = __builtin_amdgcn_mfma_f32_16x16x32_bf16(a, b[tn], acc[tm][tn], 0, 0, 0);
                }
            }
        }
    }

    const float ns2 = ns2p[0];
    const float* isig = ws + WS_ISIG_CONV + n * 128;
    #pragma unroll
    for (int tn = 0; tn < 4; ++tn) {
        const int o = wx * 64 + tn * 16 + lm;
        const float sg = isig[o];
        const float bb = b_conv[o];
        #pragma unroll
        for (int tm = 0; tm < 4; ++tm) {
            const int ox0 = X0 + wy * 64 + tm * 16 + quad * 4;
            float4 nz = *(const float4*)&noise2[((size_t)n * 256 + oy) * 256 + ox0];
            float4 outv;
            float val;
            val = acc[tm][tn][0] * sg + bb + ns2 * nz.x; outv.x = val > 0.f ? val : 0.2f * val;
            val = acc[tm][tn][1] * sg + bb + ns2 * nz.y; outv.y = val > 0.f ? val : 0.2f * val;
            val = acc[tm][tn][2] * sg + bb + ns2 * nz.z; outv.z = val > 0.f ? val : 0.2f * val;
            val = acc[tm][tn][3] * sg + bb + ns2 * nz.w; outv.w = val > 0.f ? val : 0.2f * val;
            *(float4*)&h2[(((size_t)n * 128 + o) * 256 + oy) * 256 + ox0] = outv;
        }
    }
}

// ---------------------------------------------------------------------------
// Kernel 4: to_rgb + act + bilinear skip (unchanged)
// ---------------------------------------------------------------------------
__global__ __launch_bounds__(256) void rgb_kernel(
    const float* __restrict__ h2, const float* __restrict__ w_rgb,
    const float* __restrict__ b_rgb, const float* __restrict__ y,
    const float* __restrict__ ws, float* __restrict__ yout)
{
    const int bid = blockIdx.x;
    const int n   = bid >> 8;
    const int pix = ((bid & 255) << 8) + threadIdx.x;
    const int oy  = pix >> 8, ox = pix & 255;

    __shared__ float cw0[128], cw1[128], cw2[128];
    if (threadIdx.x < 128) {
        float s = ws[WS_S_RGB + n * 128 + threadIdx.x];
        cw0[threadIdx.x] = w_rgb[0 * 128 + threadIdx.x] * s;
        cw1[threadIdx.x] = w_rgb[1 * 128 + threadIdx.x] * s;
        cw2[threadIdx.x] = w_rgb[2 * 128 + threadIdx.x] * s;
    }
    __syncthreads();

    const float* hp = h2 + (size_t)n * 128 * 65536 + oy * 256 + ox;
    float a0 = 0.f, a1 = 0.f, a2 = 0.f;
    for (int i = 0; i < 128; ++i) {
        float hv = hp[(size_t)i * 65536];
        a0 = fmaf(hv, cw0[i], a0);
        a1 = fmaf(hv, cw1[i], a1);
        a2 = fmaf(hv, cw2[i], a2);
    }

    const int m = oy >> 1;
    int iy0, iy1; float wy0, wy1;
    if ((oy & 1) == 0) { iy0 = m > 0 ? m - 1 : 0; iy1 = m; wy0 = 0.25f; wy1 = 0.75f; }
    else               { iy0 = m; iy1 = m < 127 ? m + 1 : 127; wy0 = 0.75f; wy1 = 0.25f; }
    const int mm = ox >> 1;
    int ix0, ix1; float wx0, wx1;
    if ((ox & 1) == 0) { ix0 = mm > 0 ? mm - 1 : 0; ix1 = mm; wx0 = 0.25f; wx1 = 0.75f; }
    else               { ix0 = mm; ix1 = mm < 127 ? mm + 1 : 127; wx0 = 0.75f; wx1 = 0.25f; }

    float r[3] = { a0 + b_rgb[0], a1 + b_rgb[1], a2 + b_rgb[2] };
    #pragma unroll
    for (int c = 0; c < 3; ++c) {
        float t = r[c];
        t = t > 0.f ? t : 0.2f * t;
        const float* yp = y + ((size_t)n * 3 + c) * 128 * 128;
        float yu = wy0 * (wx0 * yp[iy0 * 128 + ix0] + wx1 * yp[iy0 * 128 + ix1])
                 + wy1 * (wx0 * yp[iy1 * 128 + ix0] + wx1 * yp[iy1 * 128 + ix1]);
        yout[(((size_t)n * 3 + c) * 256 + oy) * 256 + ox] = yu + t;
    }
}

// ---------------------------------------------------------------------------
extern "C" void kernel_launch(void* const* d_in, const int* in_sizes, int n_in,
                              void* d_out, int out_size, void* d_ws, size_t ws_size,
                              hipStream_t stream)
{
    const float* x       = (const float*)d_in[0];
    const float* v       = (const float*)d_in[1];
    const float* y       = (const float*)d_in[2];
    const float* noise1  = (const float*)d_in[3];
    const float* noise2  = (const float*)d_in[4];
    const float* w_up    = (const float*)d_in[5];
    const float* b_up    = (const float*)d_in[6];
    const float* sw_up   = (const float*)d_in[7];
    const float* sb_up   = (const float*)d_in[8];
    const float* w_conv  = (const float*)d_in[9];
    const float* b_conv  = (const float*)d_in[10];
    const float* sw_conv = (const float*)d_in[11];
    const float* sb_conv = (const float*)d_in[12];
    const float* w_rgb   = (const float*)d_in[13];
    const float* b_rgb   = (const float*)d_in[14];
    const float* sw_rgb  = (const float*)d_in[15];
    const float* sb_rgb  = (const float*)d_in[16];
    const float* ns1     = (const float*)d_in[17];
    const float* ns2     = (const float*)d_in[18];

    float* ws = (float*)d_ws;
    unsigned short* h       = (unsigned short*)((char*)d_ws + WS_H_OFF);
    unsigned short* wt_up   = (unsigned short*)((char*)d_ws + WS_WUP_OFF);
    unsigned short* wt_conv = (unsigned short*)((char*)d_ws + WS_WCONV_OFF);
    float* h2   = (float*)d_out;                 // [8,128,256,256]
    float* yout = h2 + (size_t)67108864;         // [8,3,256,256]
    // xs[8][128][128][256] bf16 = 67.1 MB, parked in the h2 region of d_out.
    unsigned short* xs = (unsigned short*)d_out;

    style_kernel<<<8, 256, 0, stream>>>(v, sw_up, sb_up, w_up, sw_conv, sb_conv,
                                        w_conv, sw_rgb, sb_rgb, ws);
    prepack_up<<<216, 256, 0, stream>>>(w_up, wt_up);
    prepack_conv<<<108, 256, 0, stream>>>(w_conv, wt_conv);
    prestyle_x<<<1024, 256, 0, stream>>>(x, ws, xs);
    upconv_mfma<<<dim3(4, 256, 8), 256, 0, stream>>>(xs, wt_up, b_up, noise1, ns1, ws, h);
    conv_mfma<<<dim3(2, 256, 8), 256, 0, stream>>>(h, wt_conv, b_conv, noise2, ns2, ws, h2);
    rgb_kernel<<<2048, 256, 0, stream>>>(h2, w_rgb, b_rgb, y, ws, yout);
}

// Round 3
// 1094.657 us; speedup vs baseline: 1.3398x; 1.0584x over previous
//
#include <hip/hip_runtime.h>

// N=8, CIN=256, CINT=192, COUT=128, K=3, L=512, H=W=128, OH=OW=256, IMG=3
// R5: XCD-aware block remap (T1) for both MFMA kernels.
//  - conv grid 4096 -> 1D, w=(id%8)*512+id/8: XCD k owns image n=k, oy ascending.
//    Adjacent-oy blocks (sharing 2/3 halo rows) now share an L2 -> h fetched ~1x.
//  - upconv grid 8192 -> 1D, w=(id%8)*1024+id/8: 8 blocks sharing xs rows co-locate.
//  - weights become XCD-L2-resident. Everything else unchanged from R4.

using bfrag = __attribute__((ext_vector_type(8))) short;   // 8 bf16 (A/B frag)
using ffrag = __attribute__((ext_vector_type(4))) float;   // 4 f32 (C/D frag)

// ws float-index offsets (styles / inv-sigmas)
#define WS_S_UP      0        // 8*256
#define WS_ISIG_UP   2048     // 8*192
#define WS_S_CONV    3584     // 8*192
#define WS_ISIG_CONV 5120     // 8*128
#define WS_S_RGB     6144     // 8*128
// ws byte offsets (bf16 tensors)
#define WS_H_OFF     32768ull                       // ushort h[8][256][256][192]  (y,x,ci!)
#define H_ELEMS      (8ull*192*256*256)             // 100,663,296
#define WS_WUP_OFF   (WS_H_OFF + 2ull*H_ELEMS)      // frag-major up weights
#define WUP_ELEMS    (9*8*12*64*8)                  // 442368 (tap,kc,ob,lane,e)
#define WS_WCONV_OFF (WS_WUP_OFF + 2ull*WUP_ELEMS)  // frag-major conv weights
#define WCONV_ELEMS  (9*6*8*64*8)                   // 221184

__device__ __forceinline__ unsigned short f2bf(float f) {
    unsigned u = __float_as_uint(f);
    return (unsigned short)((u + 0x7fffu + ((u >> 16) & 1u)) >> 16);
}

// ---------------------------------------------------------------------------
// Kernel 1: styles + inverse demod sigmas (fp32, unchanged)
// ---------------------------------------------------------------------------
__global__ __launch_bounds__(256) void style_kernel(
    const float* __restrict__ v,
    const float* __restrict__ sw_up, const float* __restrict__ sb_up,
    const float* __restrict__ w_up,
    const float* __restrict__ sw_conv, const float* __restrict__ sb_conv,
    const float* __restrict__ w_conv,
    const float* __restrict__ sw_rgb, const float* __restrict__ sb_rgb,
    float* __restrict__ ws)
{
    const int n = blockIdx.x;
    const int t = threadIdx.x;
    __shared__ float sup[256];
    __shared__ float sconv[192];
    const float* vp = v + n * 512;
    {
        float a = 0.f;
        const float* r = sw_up + (size_t)t * 512;
        for (int l = 0; l < 512; ++l) a = fmaf(vp[l], r[l], a);
        float s = a + sb_up[t] + 1.0f;
        sup[t] = s;
        ws[WS_S_UP + n * 256 + t] = s;
    }
    if (t < 192) {
        float a = 0.f;
        const float* r = sw_conv + (size_t)t * 512;
        for (int l = 0; l < 512; ++l) a = fmaf(vp[l], r[l], a);
        float s = a + sb_conv[t] + 1.0f;
        sconv[t] = s;
        ws[WS_S_CONV + n * 192 + t] = s;
    }
    if (t < 128) {
        float a = 0.f;
        const float* r = sw_rgb + (size_t)t * 512;
        for (int l = 0; l < 512; ++l) a = fmaf(vp[l], r[l], a);
        ws[WS_S_RGB + n * 128 + t] = a + sb_rgb[t] + 1.0f;
    }
    __syncthreads();
    if (t < 192) {
        float sum = 0.f;
        for (int i = 0; i < 256; ++i) {
            const float* w = w_up + ((size_t)i * 192 + t) * 9;
            float wsq = 0.f;
            #pragma unroll
            for (int k = 0; k < 9; ++k) wsq = fmaf(w[k], w[k], wsq);
            sum = fmaf(sup[i] * sup[i], wsq, sum);
        }
        ws[WS_ISIG_UP + n * 192 + t] = 1.0f / sqrtf(sum + 1e-8f);
    }
    if (t < 128) {
        float sum = 0.f;
        for (int i = 0; i < 192; ++i) {
            const float* w = w_conv + ((size_t)t * 192 + i) * 9;
            float wsq = 0.f;
            #pragma unroll
            for (int k = 0; k < 9; ++k) wsq = fmaf(w[k], w[k], wsq);
            sum = fmaf(sconv[i] * sconv[i], wsq, sum);
        }
        ws[WS_ISIG_CONV + n * 128 + t] = 1.0f / sqrtf(sum + 1e-8f);
    }
}

// ---------------------------------------------------------------------------
// Weight prepack: fragment-major. frag = ((tap*KC + kc)*OB + ob); each frag is
// 64 lanes x 8 bf16: elem(lane,e) = W[o = ob*16 + (lane&15)][ci = kc*32 + (lane>>4)*8 + e]
// ---------------------------------------------------------------------------
__global__ __launch_bounds__(256) void prepack_up(
    const float* __restrict__ w_up, unsigned short* __restrict__ out)
{
    int t = blockIdx.x * 256 + threadIdx.x;   // frag*64 + lane
    if (t >= 9 * 8 * 12 * 64) return;
    int lane = t & 63;
    int f = t >> 6;                           // (tap*8 + kc)*12 + ob
    int ob = f % 12;
    int rest = f / 12;
    int kc = rest & 7;
    int tap = rest >> 3;
    int o = ob * 16 + (lane & 15);
    int ci0 = kc * 32 + (lane >> 4) * 8;
    unsigned short tmp[8];
    #pragma unroll
    for (int e = 0; e < 8; ++e)               // w_up layout [ci][o][tap]
        tmp[e] = f2bf(w_up[((size_t)((ci0 + e) * 192 + o)) * 9 + tap]);
    *(int4*)&out[(size_t)t * 8] = *(const int4*)tmp;
}

__global__ __launch_bounds__(256) void prepack_conv(
    const float* __restrict__ w_conv, unsigned short* __restrict__ out)
{
    int t = blockIdx.x * 256 + threadIdx.x;
    if (t >= 9 * 6 * 8 * 64) return;
    int lane = t & 63;
    int f = t >> 6;                           // (tap*6 + kc)*8 + ob
    int ob = f & 7;
    int rest = f >> 3;
    int kc = rest % 6;
    int tap = rest / 6;
    int o = ob * 16 + (lane & 15);
    int ci0 = kc * 32 + (lane >> 4) * 8;
    unsigned short tmp[8];
    #pragma unroll
    for (int e = 0; e < 8; ++e)               // w_conv layout [o][ci][tap]
        tmp[e] = f2bf(w_conv[((size_t)(o * 192 + ci0 + e)) * 9 + tap]);
    *(int4*)&out[(size_t)t * 8] = *(const int4*)tmp;
}

// ---------------------------------------------------------------------------
// Kernel 1b: pre-style + transpose x -> xs[n][y][x][256 ci] bf16 (unchanged)
// ---------------------------------------------------------------------------
__global__ __launch_bounds__(256) void prestyle_x(
    const float* __restrict__ x, const float* __restrict__ ws,
    unsigned short* __restrict__ xs)
{
    const int n = blockIdx.x >> 7;
    const int y = blockIdx.x & 127;
    const int tid = threadIdx.x;
    __shared__ unsigned short st[128 * 72];   // [x][64 ci + pad]

    for (int cc0 = 0; cc0 < 256; cc0 += 64) {
        if (cc0) __syncthreads();
        for (int idx = tid; idx < 64 * 128; idx += 256) {
            int c = idx >> 7;
            int xx = idx & 127;
            float s = ws[WS_S_UP + n * 256 + cc0 + c];
            float val = x[(((size_t)n * 256 + cc0 + c) * 128 + y) * 128 + xx] * s;
            st[xx * 72 + c] = f2bf(val);
        }
        __syncthreads();
        for (int idx = tid; idx < 128 * 8; idx += 256) {
            int xp = idx >> 3;
            int part = idx & 7;
            int4 v = *(const int4*)&st[xp * 72 + part * 8];
            *(int4*)&xs[(((size_t)n * 128 + y) * 128 + xp) * 256 + cc0 + part * 8] = v;
        }
    }
}

// ---------------------------------------------------------------------------
// Kernel 2: upconv MFMA GEMM. 1D grid 8192, XCD-aware remap: XCD k owns n=k.
// ---------------------------------------------------------------------------
__global__ __launch_bounds__(256, 4) void upconv_mfma(
    const unsigned short* __restrict__ xs, const unsigned short* __restrict__ wt,
    const float* __restrict__ b_up, const float* __restrict__ noise1,
    const float* __restrict__ ns1p, const float* __restrict__ ws,
    unsigned short* __restrict__ h)
{
    const int id  = blockIdx.x;                    // 0..8191
    const int w   = (id & 7) * 1024 + (id >> 3);   // XCD-contiguous work index
    const int n   = w >> 10;
    const int rem = w & 1023;
    const int oy  = rem >> 2;
    const int bx  = rem & 3;
    const int px  = bx & 1;
    const int O0  = (bx >> 1) * 96;
    const int py  = oy & 1;
    const int iy0 = oy >> 1;
    const int rows = 1 + py;
    const int ntx  = 1 + px;
    const int ntaps = rows * ntx;

    const int tid  = threadIdx.x;
    const int wave = __builtin_amdgcn_readfirstlane(tid >> 6);
    const int lane = tid & 63;
    const int lm = lane & 15, quad = lane >> 4, k0 = quad * 8;
    const int wy = wave >> 1;   // m-half (64 px)
    const int wx = wave & 1;    // n-half (48 ch)

    __shared__ __align__(16) unsigned short As[2 * 132 * 40];  // [row][xx 0..128][ci pad40]

    const bfrag* Bf = (const bfrag*)wt;       // 16B frag units
    const int ob_base = (bx >> 1) * 6 + wx * 3;   // o-block (of 16) for tn=0

    ffrag acc[4][3] = {};

    for (int kc = 0; kc < 8; ++kc) {
        const int c0 = kc * 32;
        __syncthreads();
        // stage A: rows*129*4 16B units, pure copy from xs
        {
            const int tot = rows * 516;          // 129*4
            for (int idx = tid; idx < tot; idx += 256) {
                int r = idx / 516;
                int rem2 = idx - r * 516;
                int xx = rem2 >> 2, u = rem2 & 3;
                int iy = iy0 + r;
                int4 v = {0, 0, 0, 0};
                if (iy < 128 && xx < 128)
                    v = *(const int4*)&xs[(((size_t)n * 128 + iy) * 128 + xx) * 256 + c0 + u * 8];
                *(int4*)&As[(r * 132 + xx) * 40 + u * 8] = v;
            }
        }
        __syncthreads();
        for (int t = 0; t < ntaps; ++t) {
            int rs = (ntx == 2) ? (t >> 1) : t;
            int cs = (ntx == 2) ? (t & 1) : 0;
            int ky = py ? (rs ? 0 : 2) : 1;
            int kx = px ? (cs ? 0 : 2) : 1;
            const bfrag* bp = Bf + ((size_t)(((ky * 3 + kx) * 8 + kc) * 12 + ob_base)) * 64 + lane;
            bfrag b[3];
            #pragma unroll
            for (int tn = 0; tn < 3; ++tn)
                b[tn] = bp[tn * 64];             // coalesced 1KB global load, L2-hit
            #pragma unroll
            for (int tm = 0; tm < 4; ++tm) {
                bfrag a = *(const bfrag*)&As[(rs * 132 + wy * 64 + tm * 16 + lm + cs) * 40 + k0];
                #pragma unroll
                for (int tn = 0; tn < 3; ++tn)
                    acc[tm][tn] = __builtin_amdgcn_mfma_f32_16x16x32_bf16(a, b[tn], acc[tm][tn], 0, 0, 0);
            }
        }
    }

    // epilogue: demod + bias + noise + leaky, fold s_conv, write [oy][ox][ci]
    const float ns1 = ns1p[0];
    const float* isig  = ws + WS_ISIG_UP + n * 192;
    const float* sconv = ws + WS_S_CONV + n * 192;
    #pragma unroll
    for (int tn = 0; tn < 3; ++tn) {
        const int o = O0 + wx * 48 + tn * 16 + lm;
        const float sg = isig[o];
        const float bb = b_up[o];
        const float sc = sconv[o];
        #pragma unroll
        for (int tm = 0; tm < 4; ++tm) {
            #pragma unroll
            for (int r = 0; r < 4; ++r) {
                int m = wy * 64 + tm * 16 + quad * 4 + r;   // C/D: row=quad*4+reg, col=lane&15
                int ox = 2 * m + px;
                float val = acc[tm][tn][r] * sg + bb
                          + ns1 * noise1[((size_t)n * 256 + oy) * 256 + ox];
                val = val > 0.f ? val : 0.2f * val;
                h[(((size_t)n * 256 + oy) * 256 + ox) * 192 + o] = f2bf(val * sc);
            }
        }
    }
}

// ---------------------------------------------------------------------------
// Kernel 3: 3x3 conv MFMA GEMM. 1D grid 4096, XCD-aware remap: XCD k owns n=k,
// oy ascending -> halo rows hit L2.
// ---------------------------------------------------------------------------
__global__ __launch_bounds__(256, 4) void conv_mfma(
    const unsigned short* __restrict__ h, const unsigned short* __restrict__ wt,
    const float* __restrict__ b_conv, const float* __restrict__ noise2,
    const float* __restrict__ ns2p, const float* __restrict__ ws,
    float* __restrict__ h2)
{
    const int id  = blockIdx.x;                   // 0..4095
    const int w   = (id & 7) * 512 + (id >> 3);   // XCD-contiguous work index
    const int n   = w >> 9;
    const int rem = w & 511;
    const int oy  = rem >> 1;
    const int X0  = (rem & 1) * 128;
    const int tid  = threadIdx.x;
    const int wave = __builtin_amdgcn_readfirstlane(tid >> 6);
    const int lane = tid & 63;
    const int lm = lane & 15, quad = lane >> 4, k0 = quad * 8;
    const int wy = wave >> 1, wx = wave & 1;

    __shared__ __align__(16) unsigned short As[3 * 132 * 40];  // [dy][xx 0..129][ci pad40]

    const bfrag* Bf = (const bfrag*)wt;
    const int ob_base = wx * 4;

    ffrag acc[4][4] = {};

    for (int kc = 0; kc < 6; ++kc) {
        const int c0 = kc * 32;
        __syncthreads();
        // stage A: 3*130*4 16B units, pure copy with edge zeroing
        for (int idx = tid; idx < 1560; idx += 256) {
            int r = idx / 520;
            int rem2 = idx - r * 520;
            int xx = rem2 >> 2, u = rem2 & 3;
            int iy = oy - 1 + r;
            int ix = X0 - 1 + xx;
            int4 v = {0, 0, 0, 0};
            if (iy >= 0 && iy < 256 && ix >= 0 && ix < 256)
                v = *(const int4*)&h[(((size_t)n * 256 + iy) * 256 + ix) * 192 + c0 + u * 8];
            *(int4*)&As[(r * 132 + xx) * 40 + u * 8] = v;
        }
        __syncthreads();
        for (int dy = 0; dy < 3; ++dy) {
            for (int dx = 0; dx < 3; ++dx) {
                const bfrag* bp = Bf + ((size_t)(((dy * 3 + dx) * 6 + kc) * 8 + ob_base)) * 64 + lane;
                bfrag b[4];
                #pragma unroll
                for (int tn = 0; tn < 4; ++tn)
                    b[tn] = bp[tn * 64];         // coalesced 1KB global load, L2-hit
                #pragma unroll
                for (int tm = 0; tm < 4; ++tm) {
                    bfrag a = *(const bfrag*)&As[(dy * 132 + wy * 64 + tm * 16 + lm + dx) * 40 + k0];
                    #pragma unroll
                    for (int tn = 0; tn < 4; ++tn)
                        acc[tm][tn] = __builtin_amdgcn_mfma_f32_16x16x32_bf16(a, b[tn], acc[tm][tn], 0, 0, 0);
                }
            }
        }
    }

    const float ns2 = ns2p[0];
    const float* isig = ws + WS_ISIG_CONV + n * 128;
    #pragma unroll
    for (int tn = 0; tn < 4; ++tn) {
        const int o = wx * 64 + tn * 16 + lm;
        const float sg = isig[o];
        const float bb = b_conv[o];
        #pragma unroll
        for (int tm = 0; tm < 4; ++tm) {
            const int ox0 = X0 + wy * 64 + tm * 16 + quad * 4;
            float4 nz = *(const float4*)&noise2[((size_t)n * 256 + oy) * 256 + ox0];
            float4 outv;
            float val;
            val = acc[tm][tn][0] * sg + bb + ns2 * nz.x; outv.x = val > 0.f ? val : 0.2f * val;
            val = acc[tm][tn][1] * sg + bb + ns2 * nz.y; outv.y = val > 0.f ? val : 0.2f * val;
            val = acc[tm][tn][2] * sg + bb + ns2 * nz.z; outv.z = val > 0.f ? val : 0.2f * val;
            val = acc[tm][tn][3] * sg + bb + ns2 * nz.w; outv.w = val > 0.f ? val : 0.2f * val;
            *(float4*)&h2[(((size_t)n * 128 + o) * 256 + oy) * 256 + ox0] = outv;
        }
    }
}

// ---------------------------------------------------------------------------
// Kernel 4: to_rgb + act + bilinear skip (unchanged)
// ---------------------------------------------------------------------------
__global__ __launch_bounds__(256) void rgb_kernel(
    const float* __restrict__ h2, const float* __restrict__ w_rgb,
    const float* __restrict__ b_rgb, const float* __restrict__ y,
    const float* __restrict__ ws, float* __restrict__ yout)
{
    const int bid = blockIdx.x;
    const int n   = bid >> 8;
    const int pix = ((bid & 255) << 8) + threadIdx.x;
    const int oy  = pix >> 8, ox = pix & 255;

    __shared__ float cw0[128], cw1[128], cw2[128];
    if (threadIdx.x < 128) {
        float s = ws[WS_S_RGB + n * 128 + threadIdx.x];
        cw0[threadIdx.x] = w_rgb[0 * 128 + threadIdx.x] * s;
        cw1[threadIdx.x] = w_rgb[1 * 128 + threadIdx.x] * s;
        cw2[threadIdx.x] = w_rgb[2 * 128 + threadIdx.x] * s;
    }
    __syncthreads();

    const float* hp = h2 + (size_t)n * 128 * 65536 + oy * 256 + ox;
    float a0 = 0.f, a1 = 0.f, a2 = 0.f;
    for (int i = 0; i < 128; ++i) {
        float hv = hp[(size_t)i * 65536];
        a0 = fmaf(hv, cw0[i], a0);
        a1 = fmaf(hv, cw1[i], a1);
        a2 = fmaf(hv, cw2[i], a2);
    }

    const int m = oy >> 1;
    int iy0, iy1; float wy0, wy1;
    if ((oy & 1) == 0) { iy0 = m > 0 ? m - 1 : 0; iy1 = m; wy0 = 0.25f; wy1 = 0.75f; }
    else               { iy0 = m; iy1 = m < 127 ? m + 1 : 127; wy0 = 0.75f; wy1 = 0.25f; }
    const int mm = ox >> 1;
    int ix0, ix1; float wx0, wx1;
    if ((ox & 1) == 0) { ix0 = mm > 0 ? mm - 1 : 0; ix1 = mm; wx0 = 0.25f; wx1 = 0.75f; }
    else               { ix0 = mm; ix1 = mm < 127 ? mm + 1 : 127; wx0 = 0.75f; wx1 = 0.25f; }

    float r[3] = { a0 + b_rgb[0], a1 + b_rgb[1], a2 + b_rgb[2] };
    #pragma unroll
    for (int c = 0; c < 3; ++c) {
        float t = r[c];
        t = t > 0.f ? t : 0.2f * t;
        const float* yp = y + ((size_t)n * 3 + c) * 128 * 128;
        float yu = wy0 * (wx0 * yp[iy0 * 128 + ix0] + wx1 * yp[iy0 * 128 + ix1])
                 + wy1 * (wx0 * yp[iy1 * 128 + ix0] + wx1 * yp[iy1 * 128 + ix1]);
        yout[(((size_t)n * 3 + c) * 256 + oy) * 256 + ox] = yu + t;
    }
}

// ---------------------------------------------------------------------------
extern "C" void kernel_launch(void* const* d_in, const int* in_sizes, int n_in,
                              void* d_out, int out_size, void* d_ws, size_t ws_size,
                              hipStream_t stream)
{
    const float* x       = (const float*)d_in[0];
    const float* v       = (const float*)d_in[1];
    const float* y       = (const float*)d_in[2];
    const float* noise1  = (const float*)d_in[3];
    const float* noise2  = (const float*)d_in[4];
    const float* w_up    = (const float*)d_in[5];
    const float* b_up    = (const float*)d_in[6];
    const float* sw_up   = (const float*)d_in[7];
    const float* sb_up   = (const float*)d_in[8];
    const float* w_conv  = (const float*)d_in[9];
    const float* b_conv  = (const float*)d_in[10];
    const float* sw_conv = (const float*)d_in[11];
    const float* sb_conv = (const float*)d_in[12];
    const float* w_rgb   = (const float*)d_in[13];
    const float* b_rgb   = (const float*)d_in[14];
    const float* sw_rgb  = (const float*)d_in[15];
    const float* sb_rgb  = (const float*)d_in[16];
    const float* ns1     = (const float*)d_in[17];
    const float* ns2     = (const float*)d_in[18];

    float* ws = (float*)d_ws;
    unsigned short* h       = (unsigned short*)((char*)d_ws + WS_H_OFF);
    unsigned short* wt_up   = (unsigned short*)((char*)d_ws + WS_WUP_OFF);
    unsigned short* wt_conv = (unsigned short*)((char*)d_ws + WS_WCONV_OFF);
    float* h2   = (float*)d_out;                 // [8,128,256,256]
    float* yout = h2 + (size_t)67108864;         // [8,3,256,256]
    // xs[8][128][128][256] bf16 = 67.1 MB, parked in the h2 region of d_out.
    unsigned short* xs = (unsigned short*)d_out;

    style_kernel<<<8, 256, 0, stream>>>(v, sw_up, sb_up, w_up, sw_conv, sb_conv,
                                        w_conv, sw_rgb, sb_rgb, ws);
    prepack_up<<<216, 256, 0, stream>>>(w_up, wt_up);
    prepack_conv<<<108, 256, 0, stream>>>(w_conv, wt_conv);
    prestyle_x<<<1024, 256, 0, stream>>>(x, ws, xs);
    upconv_mfma<<<8192, 256, 0, stream>>>(xs, wt_up, b_up, noise1, ns1, ws, h);
    conv_mfma<<<4096, 256, 0, stream>>>(h, wt_conv, b_conv, noise2, ns2, ws, h2);
    rgb_kernel<<<2048, 256, 0, stream>>>(h2, w_rgb, b_rgb, y, ws, yout);
}

// Round 4
// 1027.321 us; speedup vs baseline: 1.4276x; 1.0655x over previous
//
#include <hip/hip_runtime.h>

// N=8, CIN=256, CINT=192, COUT=128, K=3, L=512, H=W=128, OH=OW=256, IMG=3
// R6: double B reuse per wave (row-pair blocks) + B prefetch.
//  - conv: block = oy-pair x 128px x 128o, wave acc [2][4][4]; B frags double-
//    buffered one tap ahead; B L2 traffic halves.
//  - upconv: same-parity oy pairs (4j+q, 4j+q+2) share tap sets; all tap-group
//    B frags (<=12) prefetched per kc chunk.
//  - __launch_bounds__(256,2): acc 96-128 VGPRs needs the 256-reg budget.

using bfrag = __attribute__((ext_vector_type(8))) short;   // 8 bf16 (A/B frag)
using ffrag = __attribute__((ext_vector_type(4))) float;   // 4 f32 (C/D frag)

// ws float-index offsets (styles / inv-sigmas)
#define WS_S_UP      0        // 8*256
#define WS_ISIG_UP   2048     // 8*192
#define WS_S_CONV    3584     // 8*192
#define WS_ISIG_CONV 5120     // 8*128
#define WS_S_RGB     6144     // 8*128
// ws byte offsets (bf16 tensors)
#define WS_H_OFF     32768ull                       // ushort h[8][256][256][192]  (y,x,ci!)
#define H_ELEMS      (8ull*192*256*256)             // 100,663,296
#define WS_WUP_OFF   (WS_H_OFF + 2ull*H_ELEMS)      // frag-major up weights
#define WUP_ELEMS    (9*8*12*64*8)                  // 442368 (tap,kc,ob,lane,e)
#define WS_WCONV_OFF (WS_WUP_OFF + 2ull*WUP_ELEMS)  // frag-major conv weights
#define WCONV_ELEMS  (9*6*8*64*8)                   // 221184

__device__ __forceinline__ unsigned short f2bf(float f) {
    unsigned u = __float_as_uint(f);
    return (unsigned short)((u + 0x7fffu + ((u >> 16) & 1u)) >> 16);
}

// ---------------------------------------------------------------------------
// Kernel 1: styles + inverse demod sigmas (fp32, unchanged)
// ---------------------------------------------------------------------------
__global__ __launch_bounds__(256) void style_kernel(
    const float* __restrict__ v,
    const float* __restrict__ sw_up, const float* __restrict__ sb_up,
    const float* __restrict__ w_up,
    const float* __restrict__ sw_conv, const float* __restrict__ sb_conv,
    const float* __restrict__ w_conv,
    const float* __restrict__ sw_rgb, const float* __restrict__ sb_rgb,
    float* __restrict__ ws)
{
    const int n = blockIdx.x;
    const int t = threadIdx.x;
    __shared__ float sup[256];
    __shared__ float sconv[192];
    const float* vp = v + n * 512;
    {
        float a = 0.f;
        const float* r = sw_up + (size_t)t * 512;
        for (int l = 0; l < 512; ++l) a = fmaf(vp[l], r[l], a);
        float s = a + sb_up[t] + 1.0f;
        sup[t] = s;
        ws[WS_S_UP + n * 256 + t] = s;
    }
    if (t < 192) {
        float a = 0.f;
        const float* r = sw_conv + (size_t)t * 512;
        for (int l = 0; l < 512; ++l) a = fmaf(vp[l], r[l], a);
        float s = a + sb_conv[t] + 1.0f;
        sconv[t] = s;
        ws[WS_S_CONV + n * 192 + t] = s;
    }
    if (t < 128) {
        float a = 0.f;
        const float* r = sw_rgb + (size_t)t * 512;
        for (int l = 0; l < 512; ++l) a = fmaf(vp[l], r[l], a);
        ws[WS_S_RGB + n * 128 + t] = a + sb_rgb[t] + 1.0f;
    }
    __syncthreads();
    if (t < 192) {
        float sum = 0.f;
        for (int i = 0; i < 256; ++i) {
            const float* w = w_up + ((size_t)i * 192 + t) * 9;
            float wsq = 0.f;
            #pragma unroll
            for (int k = 0; k < 9; ++k) wsq = fmaf(w[k], w[k], wsq);
            sum = fmaf(sup[i] * sup[i], wsq, sum);
        }
        ws[WS_ISIG_UP + n * 192 + t] = 1.0f / sqrtf(sum + 1e-8f);
    }
    if (t < 128) {
        float sum = 0.f;
        for (int i = 0; i < 192; ++i) {
            const float* w = w_conv + ((size_t)t * 192 + i) * 9;
            float wsq = 0.f;
            #pragma unroll
            for (int k = 0; k < 9; ++k) wsq = fmaf(w[k], w[k], wsq);
            sum = fmaf(sconv[i] * sconv[i], wsq, sum);
        }
        ws[WS_ISIG_CONV + n * 128 + t] = 1.0f / sqrtf(sum + 1e-8f);
    }
}

// ---------------------------------------------------------------------------
// Weight prepack: fragment-major (unchanged layouts from R4/R5)
// ---------------------------------------------------------------------------
__global__ __launch_bounds__(256) void prepack_up(
    const float* __restrict__ w_up, unsigned short* __restrict__ out)
{
    int t = blockIdx.x * 256 + threadIdx.x;   // frag*64 + lane
    if (t >= 9 * 8 * 12 * 64) return;
    int lane = t & 63;
    int f = t >> 6;                           // (tap*8 + kc)*12 + ob
    int ob = f % 12;
    int rest = f / 12;
    int kc = rest & 7;
    int tap = rest >> 3;
    int o = ob * 16 + (lane & 15);
    int ci0 = kc * 32 + (lane >> 4) * 8;
    unsigned short tmp[8];
    #pragma unroll
    for (int e = 0; e < 8; ++e)               // w_up layout [ci][o][tap]
        tmp[e] = f2bf(w_up[((size_t)((ci0 + e) * 192 + o)) * 9 + tap]);
    *(int4*)&out[(size_t)t * 8] = *(const int4*)tmp;
}

__global__ __launch_bounds__(256) void prepack_conv(
    const float* __restrict__ w_conv, unsigned short* __restrict__ out)
{
    int t = blockIdx.x * 256 + threadIdx.x;
    if (t >= 9 * 6 * 8 * 64) return;
    int lane = t & 63;
    int f = t >> 6;                           // (tap*6 + kc)*8 + ob
    int ob = f & 7;
    int rest = f >> 3;
    int kc = rest % 6;
    int tap = rest / 6;
    int o = ob * 16 + (lane & 15);
    int ci0 = kc * 32 + (lane >> 4) * 8;
    unsigned short tmp[8];
    #pragma unroll
    for (int e = 0; e < 8; ++e)               // w_conv layout [o][ci][tap]
        tmp[e] = f2bf(w_conv[((size_t)(o * 192 + ci0 + e)) * 9 + tap]);
    *(int4*)&out[(size_t)t * 8] = *(const int4*)tmp;
}

// ---------------------------------------------------------------------------
// Kernel 1b: pre-style + transpose x -> xs[n][y][x][256 ci] bf16 (unchanged)
// ---------------------------------------------------------------------------
__global__ __launch_bounds__(256) void prestyle_x(
    const float* __restrict__ x, const float* __restrict__ ws,
    unsigned short* __restrict__ xs)
{
    const int n = blockIdx.x >> 7;
    const int y = blockIdx.x & 127;
    const int tid = threadIdx.x;
    __shared__ unsigned short st[128 * 72];   // [x][64 ci + pad]

    for (int cc0 = 0; cc0 < 256; cc0 += 64) {
        if (cc0) __syncthreads();
        for (int idx = tid; idx < 64 * 128; idx += 256) {
            int c = idx >> 7;
            int xx = idx & 127;
            float s = ws[WS_S_UP + n * 256 + cc0 + c];
            float val = x[(((size_t)n * 256 + cc0 + c) * 128 + y) * 128 + xx] * s;
            st[xx * 72 + c] = f2bf(val);
        }
        __syncthreads();
        for (int idx = tid; idx < 128 * 8; idx += 256) {
            int xp = idx >> 3;
            int part = idx & 7;
            int4 v = *(const int4*)&st[xp * 72 + part * 8];
            *(int4*)&xs[(((size_t)n * 128 + y) * 128 + xp) * 256 + cc0 + part * 8] = v;
        }
    }
}

// ---------------------------------------------------------------------------
// Kernel 2: upconv MFMA GEMM, same-parity oy-pair blocks.
// Block = (n, j, q, px, o-half): outputs oy = 4j+q and 4j+q+2, 128 px (parity
// px), 96 o.  Staged input rows iy = 2j..2j+1+q.  Tap set shared by both rows.
// ---------------------------------------------------------------------------
__global__ __launch_bounds__(256, 2) void upconv_mfma(
    const unsigned short* __restrict__ xs, const unsigned short* __restrict__ wt,
    const float* __restrict__ b_up, const float* __restrict__ noise1,
    const float* __restrict__ ns1p, const float* __restrict__ ws,
    unsigned short* __restrict__ h)
{
    const int id  = blockIdx.x;                    // 0..4095
    const int w   = (id & 7) * 512 + (id >> 3);    // XCD k owns n=k
    const int n   = w >> 9;
    const int rem = w & 511;                       // j*8 + q*4 + px*2 + obh
    const int j   = rem >> 3;
    const int q   = (rem >> 2) & 1;                // oy parity
    const int px  = (rem >> 1) & 1;                // ox parity
    const int O0  = (rem & 1) * 96;
    const int nrows = 2 + q;                       // staged xs rows
    const int ng    = (1 + q) * (1 + px);          // tap groups (<=4)

    const int tid  = threadIdx.x;
    const int wave = __builtin_amdgcn_readfirstlane(tid >> 6);
    const int lane = tid & 63;
    const int lm = lane & 15, quad = lane >> 4, k0 = quad * 8;
    const int wy = wave >> 1;   // x-half (64 of 128 m-px)
    const int wx = wave & 1;    // o-half (48 ch)

    __shared__ __align__(16) unsigned short As[3 * 132 * 40];  // [r][xx 0..128][ci pad40]

    const bfrag* Bf = (const bfrag*)wt;
    const int ob_base = (rem & 1) * 6 + wx * 3;

    ffrag acc[2][4][3] = {};   // [row01][tm][tn]

    for (int kc = 0; kc < 8; ++kc) {
        const int c0 = kc * 32;
        __syncthreads();
        {
            const int tot = nrows * 516;          // 129*4 per row
            for (int idx = tid; idx < tot; idx += 256) {
                int r = idx / 516;
                int rem2 = idx - r * 516;
                int xx = rem2 >> 2, u = rem2 & 3;
                int iy = 2 * j + r;
                int4 v = {0, 0, 0, 0};
                if (iy < 128 && xx < 128)
                    v = *(const int4*)&xs[(((size_t)n * 128 + iy) * 128 + xx) * 256 + c0 + u * 8];
                *(int4*)&As[(r * 132 + xx) * 40 + u * 8] = v;
            }
        }
        __syncthreads();
        // prefetch all tap groups' B frags (<=12, static-indexed)
        bfrag ball[4][3];
        #pragma unroll
        for (int g = 0; g < 4; ++g) {
            if (g < ng) {
                int rs = px ? (g >> 1) : g;
                int cs = px ? (g & 1) : 0;
                int ky = q ? (rs ? 0 : 2) : 1;
                int kx = px ? (cs ? 0 : 2) : 1;
                const bfrag* p = Bf + ((size_t)(((ky * 3 + kx) * 8 + kc) * 12 + ob_base)) * 64 + lane;
                #pragma unroll
                for (int tn = 0; tn < 3; ++tn) ball[g][tn] = p[tn * 64];
            }
        }
        #pragma unroll
        for (int g = 0; g < 4; ++g) {
            if (g < ng) {
                int rs = px ? (g >> 1) : g;
                int cs = px ? (g & 1) : 0;
                #pragma unroll
                for (int r01 = 0; r01 < 2; ++r01) {
                    int arow = q ? (r01 + rs) : r01;
                    #pragma unroll
                    for (int tm = 0; tm < 4; ++tm) {
                        bfrag a = *(const bfrag*)&As[(arow * 132 + wy * 64 + tm * 16 + lm + cs) * 40 + k0];
                        #pragma unroll
                        for (int tn = 0; tn < 3; ++tn)
                            acc[r01][tm][tn] = __builtin_amdgcn_mfma_f32_16x16x32_bf16(
                                a, ball[g][tn], acc[r01][tm][tn], 0, 0, 0);
                    }
                }
            }
        }
    }

    // epilogue: demod + bias + noise + leaky, fold s_conv, write [oy][ox][ci]
    const float ns1 = ns1p[0];
    const float* isig  = ws + WS_ISIG_UP + n * 192;
    const float* sconv = ws + WS_S_CONV + n * 192;
    #pragma unroll
    for (int r01 = 0; r01 < 2; ++r01) {
        const int oy = 4 * j + q + 2 * r01;
        #pragma unroll
        for (int tn = 0; tn < 3; ++tn) {
            const int o = O0 + wx * 48 + tn * 16 + lm;
            const float sg = isig[o];
            const float bb = b_up[o];
            const float sc = sconv[o];
            #pragma unroll
            for (int tm = 0; tm < 4; ++tm) {
                #pragma unroll
                for (int r = 0; r < 4; ++r) {
                    int m = wy * 64 + tm * 16 + quad * 4 + r;
                    int ox = 2 * m + px;
                    float val = acc[r01][tm][tn][r] * sg + bb
                              + ns1 * noise1[((size_t)n * 256 + oy) * 256 + ox];
                    val = val > 0.f ? val : 0.2f * val;
                    h[(((size_t)n * 256 + oy) * 256 + ox) * 192 + o] = f2bf(val * sc);
                }
            }
        }
    }
}

// ---------------------------------------------------------------------------
// Kernel 3: 3x3 conv MFMA GEMM, oy-pair blocks.  Block = (n, oyp, x-half):
// 2 rows x 128 px x 128 o.  As = 4 h-rows.  B double-buffered one tap ahead.
// ---------------------------------------------------------------------------
__global__ __launch_bounds__(256, 2) void conv_mfma(
    const unsigned short* __restrict__ h, const unsigned short* __restrict__ wt,
    const float* __restrict__ b_conv, const float* __restrict__ noise2,
    const float* __restrict__ ns2p, const float* __restrict__ ws,
    float* __restrict__ h2)
{
    const int id  = blockIdx.x;                   // 0..2047
    const int w   = (id & 7) * 256 + (id >> 3);   // XCD k owns n=k
    const int n   = w >> 8;
    const int rem = w & 255;
    const int oy0 = (rem >> 1) * 2;               // row pair oy0, oy0+1
    const int X0  = (rem & 1) * 128;
    const int tid  = threadIdx.x;
    const int wave = __builtin_amdgcn_readfirstlane(tid >> 6);
    const int lane = tid & 63;
    const int lm = lane & 15, quad = lane >> 4, k0 = quad * 8;
    const int wy = wave >> 1, wx = wave & 1;

    __shared__ __align__(16) unsigned short As[4 * 132 * 40];  // rows oy0-1..oy0+2

    const bfrag* Bf = (const bfrag*)wt;
    const int ob_base = wx * 4;

    ffrag acc[2][4][4] = {};   // [row01][tm][tn]

    for (int kc = 0; kc < 6; ++kc) {
        const int c0 = kc * 32;
        __syncthreads();
        // stage A: 4 rows * 130 xx * 4 u, pure copy with edge zeroing
        for (int idx = tid; idx < 2080; idx += 256) {
            int r = idx / 520;
            int rem2 = idx - r * 520;
            int xx = rem2 >> 2, u = rem2 & 3;
            int iy = oy0 - 1 + r;
            int ix = X0 - 1 + xx;
            int4 v = {0, 0, 0, 0};
            if (iy >= 0 && iy < 256 && ix >= 0 && ix < 256)
                v = *(const int4*)&h[(((size_t)n * 256 + iy) * 256 + ix) * 192 + c0 + u * 8];
            *(int4*)&As[(r * 132 + xx) * 40 + u * 8] = v;
        }
        __syncthreads();

        // 9 taps, B double-buffered one tap ahead (static indices via unroll)
        bfrag bb[2][4];
        {
            const bfrag* p = Bf + ((size_t)((0 * 6 + kc) * 8 + ob_base)) * 64 + lane;
            #pragma unroll
            for (int tn = 0; tn < 4; ++tn) bb[0][tn] = p[tn * 64];
        }
        #pragma unroll
        for (int t = 0; t < 9; ++t) {
            const int cur = t & 1, nxt = cur ^ 1;
            if (t < 8) {
                const bfrag* p = Bf + ((size_t)(((t + 1) * 6 + kc) * 8 + ob_base)) * 64 + lane;
                #pragma unroll
                for (int tn = 0; tn < 4; ++tn) bb[nxt][tn] = p[tn * 64];
            }
            const int dy = t / 3, dx = t % 3;
            #pragma unroll
            for (int r01 = 0; r01 < 2; ++r01) {
                #pragma unroll
                for (int tm = 0; tm < 4; ++tm) {
                    bfrag a = *(const bfrag*)&As[((r01 + dy) * 132 + wy * 64 + tm * 16 + lm + dx) * 40 + k0];
                    #pragma unroll
                    for (int tn = 0; tn < 4; ++tn)
                        acc[r01][tm][tn] = __builtin_amdgcn_mfma_f32_16x16x32_bf16(
                            a, bb[cur][tn], acc[r01][tm][tn], 0, 0, 0);
                }
            }
        }
    }

    const float ns2 = ns2p[0];
    const float* isig = ws + WS_ISIG_CONV + n * 128;
    #pragma unroll
    for (int r01 = 0; r01 < 2; ++r01) {
        const int oy = oy0 + r01;
        #pragma unroll
        for (int tn = 0; tn < 4; ++tn) {
            const int o = wx * 64 + tn * 16 + lm;
            const float sg = isig[o];
            const float bb2 = b_conv[o];
            #pragma unroll
            for (int tm = 0; tm < 4; ++tm) {
                const int ox0 = X0 + wy * 64 + tm * 16 + quad * 4;
                float4 nz = *(const float4*)&noise2[((size_t)n * 256 + oy) * 256 + ox0];
                float4 outv;
                float val;
                val = acc[r01][tm][tn][0] * sg + bb2 + ns2 * nz.x; outv.x = val > 0.f ? val : 0.2f * val;
                val = acc[r01][tm][tn][1] * sg + bb2 + ns2 * nz.y; outv.y = val > 0.f ? val : 0.2f * val;
                val = acc[r01][tm][tn][2] * sg + bb2 + ns2 * nz.z; outv.z = val > 0.f ? val : 0.2f * val;
                val = acc[r01][tm][tn][3] * sg + bb2 + ns2 * nz.w; outv.w = val > 0.f ? val : 0.2f * val;
                *(float4*)&h2[(((size_t)n * 128 + o) * 256 + oy) * 256 + ox0] = outv;
            }
        }
    }
}

// ---------------------------------------------------------------------------
// Kernel 4: to_rgb + act + bilinear skip (unchanged)
// ---------------------------------------------------------------------------
__global__ __launch_bounds__(256) void rgb_kernel(
    const float* __restrict__ h2, const float* __restrict__ w_rgb,
    const float* __restrict__ b_rgb, const float* __restrict__ y,
    const float* __restrict__ ws, float* __restrict__ yout)
{
    const int bid = blockIdx.x;
    const int n   = bid >> 8;
    const int pix = ((bid & 255) << 8) + threadIdx.x;
    const int oy  = pix >> 8, ox = pix & 255;

    __shared__ float cw0[128], cw1[128], cw2[128];
    if (threadIdx.x < 128) {
        float s = ws[WS_S_RGB + n * 128 + threadIdx.x];
        cw0[threadIdx.x] = w_rgb[0 * 128 + threadIdx.x] * s;
        cw1[threadIdx.x] = w_rgb[1 * 128 + threadIdx.x] * s;
        cw2[threadIdx.x] = w_rgb[2 * 128 + threadIdx.x] * s;
    }
    __syncthreads();

    const float* hp = h2 + (size_t)n * 128 * 65536 + oy * 256 + ox;
    float a0 = 0.f, a1 = 0.f, a2 = 0.f;
    for (int i = 0; i < 128; ++i) {
        float hv = hp[(size_t)i * 65536];
        a0 = fmaf(hv, cw0[i], a0);
        a1 = fmaf(hv, cw1[i], a1);
        a2 = fmaf(hv, cw2[i], a2);
    }

    const int m = oy >> 1;
    int iy0, iy1; float wy0, wy1;
    if ((oy & 1) == 0) { iy0 = m > 0 ? m - 1 : 0; iy1 = m; wy0 = 0.25f; wy1 = 0.75f; }
    else               { iy0 = m; iy1 = m < 127 ? m + 1 : 127; wy0 = 0.75f; wy1 = 0.25f; }
    const int mm = ox >> 1;
    int ix0, ix1; float wx0, wx1;
    if ((ox & 1) == 0) { ix0 = mm > 0 ? mm - 1 : 0; ix1 = mm; wx0 = 0.25f; wx1 = 0.75f; }
    else               { ix0 = mm; ix1 = mm < 127 ? mm + 1 : 127; wx0 = 0.75f; wx1 = 0.25f; }

    float r[3] = { a0 + b_rgb[0], a1 + b_rgb[1], a2 + b_rgb[2] };
    #pragma unroll
    for (int c = 0; c < 3; ++c) {
        float t = r[c];
        t = t > 0.f ? t : 0.2f * t;
        const float* yp = y + ((size_t)n * 3 + c) * 128 * 128;
        float yu = wy0 * (wx0 * yp[iy0 * 128 + ix0] + wx1 * yp[iy0 * 128 + ix1])
                 + wy1 * (wx0 * yp[iy1 * 128 + ix0] + wx1 * yp[iy1 * 128 + ix1]);
        yout[(((size_t)n * 3 + c) * 256 + oy) * 256 + ox] = yu + t;
    }
}

// ---------------------------------------------------------------------------
extern "C" void kernel_launch(void* const* d_in, const int* in_sizes, int n_in,
                              void* d_out, int out_size, void* d_ws, size_t ws_size,
                              hipStream_t stream)
{
    const float* x       = (const float*)d_in[0];
    const float* v       = (const float*)d_in[1];
    const float* y       = (const float*)d_in[2];
    const float* noise1  = (const float*)d_in[3];
    const float* noise2  = (const float*)d_in[4];
    const float* w_up    = (const float*)d_in[5];
    const float* b_up    = (const float*)d_in[6];
    const float* sw_up   = (const float*)d_in[7];
    const float* sb_up   = (const float*)d_in[8];
    const float* w_conv  = (const float*)d_in[9];
    const float* b_conv  = (const float*)d_in[10];
    const float* sw_conv = (const float*)d_in[11];
    const float* sb_conv = (const float*)d_in[12];
    const float* w_rgb   = (const float*)d_in[13];
    const float* b_rgb   = (const float*)d_in[14];
    const float* sw_rgb  = (const float*)d_in[15];
    const float* sb_rgb  = (const float*)d_in[16];
    const float* ns1     = (const float*)d_in[17];
    const float* ns2     = (const float*)d_in[18];

    float* ws = (float*)d_ws;
    unsigned short* h       = (unsigned short*)((char*)d_ws + WS_H_OFF);
    unsigned short* wt_up   = (unsigned short*)((char*)d_ws + WS_WUP_OFF);
    unsigned short* wt_conv = (unsigned short*)((char*)d_ws + WS_WCONV_OFF);
    float* h2   = (float*)d_out;                 // [8,128,256,256]
    float* yout = h2 + (size_t)67108864;         // [8,3,256,256]
    // xs[8][128][128][256] bf16 = 67.1 MB, parked in the h2 region of d_out.
    unsigned short* xs = (unsigned short*)d_out;

    style_kernel<<<8, 256, 0, stream>>>(v, sw_up, sb_up, w_up, sw_conv, sb_conv,
                                        w_conv, sw_rgb, sb_rgb, ws);
    prepack_up<<<216, 256, 0, stream>>>(w_up, wt_up);
    prepack_conv<<<108, 256, 0, stream>>>(w_conv, wt_conv);
    prestyle_x<<<1024, 256, 0, stream>>>(x, ws, xs);
    upconv_mfma<<<4096, 256, 0, stream>>>(xs, wt_up, b_up, noise1, ns1, ws, h);
    conv_mfma<<<2048, 256, 0, stream>>>(h, wt_conv, b_conv, noise2, ns2, ws, h2);
    rgb_kernel<<<2048, 256, 0, stream>>>(h2, w_rgb, b_rgb, y, ws, yout);
}